// Round 13
// baseline (245.378 us; speedup 1.0000x reference)
//
#include <hip/hip_runtime.h>
#include <hip/hip_bf16.h>

typedef __attribute__((ext_vector_type(8))) short short8;
typedef __attribute__((ext_vector_type(4))) float f32x4;
typedef __attribute__((ext_vector_type(4))) short short4v;

// Problem constants
#define BB 8
#define NN 1024
#define DD 512
#define OO 512
#define HH 8
#define HD 64
#define MM (BB * NN)  // 8192

#define QSC 0.18033688f       // 0.125 * log2(e): folded into Q at projection
#define KSHIFT -11.54156032f  // -8*log2(e): softmax shift, fused into key bias
#define KMASKED -30000.0f     // masked key: exp2 underflows to exactly 0

// Async global->LDS, 16B/lane (m97 recipe). LDS dest = wave-uniform base +
// lane*16 -> unpadded tiles.
__device__ __forceinline__ void gload_lds16(const void* g, void* l) {
  __builtin_amdgcn_global_load_lds(
      (const __attribute__((address_space(1))) void*)g,
      (__attribute__((address_space(3))) void*)l, 16, 0, 0);
}

__device__ __forceinline__ uint2 cvt4(float4 v) {
  union { uint2 u; __hip_bfloat16 h[4]; } t;
  t.h[0] = __float2bfloat16(v.x);
  t.h[1] = __float2bfloat16(v.y);
  t.h[2] = __float2bfloat16(v.z);
  t.h[3] = __float2bfloat16(v.w);
  return t.u;
}

// ---------------------------------------------------------------------------
// Weight/bias conversion (x no longer converted: GEMMs read fp32 x directly).
// ---------------------------------------------------------------------------
#define SEG_N 9
struct ConvArgs {
  const float* src[SEG_N];
  __hip_bfloat16* dst[SEG_N];
  int n4[SEG_N];
};

__global__ void convert_kernel(ConvArgs a) {
  const int t = blockIdx.y;
  const int n4 = a.n4[t];
  const float4* fs = (const float4*)a.src[t];
  uint2* d = (uint2*)a.dst[t];
  for (int i = blockIdx.x * blockDim.x + threadIdx.x; i < n4;
       i += gridDim.x * blockDim.x)
    d[i] = cvt4(fs[i]);
}

// ---------------------------------------------------------------------------
// 128x128-tile GEMM: qkv projection. A = x read as FP32 (register convert),
// B = qkv_w bf16 via global_load_lds. Q (pre-scaled QSC), K -> [B,H,N,64];
// V -> [B,H,64,N] transposed via LDS + coalesced stores.
// ---------------------------------------------------------------------------
__global__ __launch_bounds__(256) void gemm_qkv(
    const float* __restrict__ A0f, const __hip_bfloat16* __restrict__ B0,
    const __hip_bfloat16* __restrict__ bias0,
    __hip_bfloat16* __restrict__ out0, __hip_bfloat16* __restrict__ out1,
    __hip_bfloat16* __restrict__ out2, int Kd) {
  // Unpadded: As 128x32 (8KB) | Bs 128x32 (8KB)
  __shared__ __align__(16) __hip_bfloat16 smem[8192];
  __hip_bfloat16* As = smem;
  __hip_bfloat16* Bs = smem + 4096;

  const int tid  = threadIdx.x;
  const int wave = tid >> 6;
  const int lane = tid & 63;
  const int fl   = lane & 15;
  const int fk   = (lane >> 4) * 8;
  const int wm   = (wave & 1) * 64;
  const int wn   = (wave >> 1) * 64;
  const int m0   = blockIdx.y * 128;
  const int n0   = blockIdx.x * 128;
  const int glr  = lane >> 2;
  const int glc  = (lane & 3) * 8;
  const int sr   = tid >> 3;         // 0..31
  const int sc   = (tid & 7) * 4;    // 0..28

  f32x4 acc[4][4];
#pragma unroll
  for (int i = 0; i < 4; ++i)
#pragma unroll
    for (int j = 0; j < 4; ++j) acc[i][j] = (f32x4){0.f, 0.f, 0.f, 0.f};

  char* lb = (char*)smem;
  for (int k0 = 0; k0 < Kd; k0 += 32) {
    __syncthreads();
    // A: 128x32 fp32 -> bf16, 4 rounds of (load float4, convert, ds_write b64)
#pragma unroll
    for (int rnd = 0; rnd < 4; ++rnd) {
      const int row = rnd * 32 + sr;
      float4 v = *(const float4*)(A0f + (size_t)(m0 + row) * Kd + k0 + sc);
      *(uint2*)&As[row * 32 + sc] = cvt4(v);
    }
    // B: bf16 weights, async 16B/lane
    gload_lds16(B0 + (size_t)(n0 + wave * 16 + glr) * Kd + k0 + glc,
                lb + 8192 + wave * 1024 + lane * 16);
    gload_lds16(B0 + (size_t)(n0 + 64 + wave * 16 + glr) * Kd + k0 + glc,
                lb + 8192 + (wave + 4) * 1024 + lane * 16);
    __syncthreads();

    short8 af[4], bfr[4];
#pragma unroll
    for (int i = 0; i < 4; ++i)
      af[i] = *(const short8*)&As[(wm + i * 16 + fl) * 32 + fk];
#pragma unroll
    for (int j = 0; j < 4; ++j)
      bfr[j] = *(const short8*)&Bs[(wn + j * 16 + fl) * 32 + fk];
#pragma unroll
    for (int i = 0; i < 4; ++i)
#pragma unroll
      for (int j = 0; j < 4; ++j)
        acc[i][j] = __builtin_amdgcn_mfma_f32_16x16x32_bf16(af[i], bfr[j],
                                                            acc[i][j], 0, 0, 0);
  }

  const int rb = (lane >> 4) * 4;
  const int part = n0 >> 9;  // block-uniform
  if (part < 2) {
    __hip_bfloat16* dst = (part == 0) ? out0 : out1;
    const float scf = (part == 0) ? QSC : 1.0f;
#pragma unroll
    for (int j = 0; j < 4; ++j) {
      const int colb  = n0 + wn + j * 16;
      const int o     = colb & 511;
      const int headq = o >> 6;
      const int d     = (o & 63) + fl;
      const float bi  = __bfloat162float(bias0[colb + fl]);
#pragma unroll
      for (int i = 0; i < 4; ++i) {
#pragma unroll
        for (int r = 0; r < 4; ++r) {
          const int row = m0 + wm + i * 16 + rb + r;
          const int bb  = row >> 10;
          const int nn  = row & 1023;
          dst[((size_t)((bb << 3) + headq) * NN + nn) * HD + d] =
              __float2bfloat16((acc[i][j][r] + bi) * scf);
        }
      }
    }
  } else {
    // V: transpose 64x16 pieces through LDS, coalesced dwordx4 stores
    __syncthreads();  // uniform; smem free for scratch
    __hip_bfloat16* tsc = smem + wave * 1120;  // 16 x 70 per wave
    const int bb  = (m0 + wm) >> 10;
    const int nnb = (m0 + wm) & 1023;
    const int dl  = lane >> 2;
    const int cc  = (lane & 3) * 16;
#pragma unroll
    for (int j = 0; j < 4; ++j) {
      const int colb  = n0 + wn + j * 16;
      const int o     = colb & 511;
      const int headq = o >> 6;
      const int dbase = o & 63;
      const float bi  = __bfloat162float(bias0[colb + fl]);
#pragma unroll
      for (int i = 0; i < 4; ++i) {
#pragma unroll
        for (int r = 0; r < 4; ++r) {
          const int rr = i * 16 + rb + r;
          tsc[fl * 70 + rr] = __float2bfloat16(acc[i][j][r] + bi);
        }
      }
      uint4 r0 = *(const uint4*)&tsc[dl * 70 + cc];
      uint4 r1 = *(const uint4*)&tsc[dl * 70 + cc + 8];
      __hip_bfloat16* vdst =
          out2 + ((size_t)((bb << 3) + headq) * HD + dbase + dl) * NN + nnb;
      *(uint4*)&vdst[cc] = r0;
      *(uint4*)&vdst[cc + 8] = r1;
    }
  }
}

// ---------------------------------------------------------------------------
// Fused FFN + residual: block owns 32 output rows.
// stage 1: Ts = relu(h @ w1^T + b1), masked rows zeroed (into LDS)
// stage 2: out = 0.5*(Ts @ w2^T + mask*b2 + x @ wr^T + br) -> fp32 d_out
// Eliminates the 16MB t round-trip and one kernel launch.
// Wave w owns out-cols [w*128, w*128+128); rows 2x16-tiles; acc 2x8 f32x4.
// ---------------------------------------------------------------------------
__global__ __launch_bounds__(256) void ffn_fused(
    const __hip_bfloat16* __restrict__ hb, const float* __restrict__ xf,
    const __hip_bfloat16* __restrict__ w1c, const __hip_bfloat16* __restrict__ w2c,
    const __hip_bfloat16* __restrict__ wrc, const __hip_bfloat16* __restrict__ b1c,
    const __hip_bfloat16* __restrict__ b2c, const __hip_bfloat16* __restrict__ brc,
    const int* __restrict__ mask, float* __restrict__ outf) {
  __shared__ __align__(16) __hip_bfloat16 Ts[32 * 520];   // 33.3 KB
  __shared__ __align__(16) __hip_bfloat16 Asm[32 * 32];   // 2 KB
  __shared__ __align__(16) __hip_bfloat16 Bsm[512 * 32];  // 32 KB

  const int tid  = threadIdx.x;
  const int wave = tid >> 6;
  const int lane = tid & 63;
  const int fl   = lane & 15;
  const int quad = lane >> 4;
  const int fk   = quad * 8;
  const int rb   = quad * 4;
  const int m0   = blockIdx.x * 32;
  const int sr   = tid >> 3;        // 0..31
  const int sc   = (tid & 7) * 4;   // 0..28
  const int glr  = lane >> 2;
  const int glc  = (lane & 3) * 8;

  f32x4 acc[2][8];
#pragma unroll
  for (int i = 0; i < 2; ++i)
#pragma unroll
    for (int j = 0; j < 8; ++j) acc[i][j] = (f32x4){0.f, 0.f, 0.f, 0.f};

  // ---- stage 1: Ts = relu(h @ w1^T + b1)
  for (int k0 = 0; k0 < OO; k0 += 32) {
    __syncthreads();
    {  // A: h tile 32x32 bf16 (one b64 per thread)
      uint2 v = *(const uint2*)(hb + (size_t)(m0 + sr) * OO + k0 + sc);
      *(uint2*)&Asm[sr * 32 + sc] = v;
    }
#pragma unroll
    for (int c = 0; c < 8; ++c)  // B: wave's 128 out-cols of w1
      gload_lds16(w1c + (size_t)(wave * 128 + c * 16 + glr) * OO + k0 + glc,
                  (char*)Bsm + wave * 8192 + c * 1024 + lane * 16);
    __syncthreads();

    short8 af0 = *(const short8*)&Asm[fl * 32 + fk];
    short8 af1 = *(const short8*)&Asm[(16 + fl) * 32 + fk];
#pragma unroll
    for (int j = 0; j < 8; ++j) {
      const short8 bfr = *(const short8*)&Bsm[(wave * 128 + j * 16 + fl) * 32 + fk];
      acc[0][j] = __builtin_amdgcn_mfma_f32_16x16x32_bf16(af0, bfr, acc[0][j], 0, 0, 0);
      acc[1][j] = __builtin_amdgcn_mfma_f32_16x16x32_bf16(af1, bfr, acc[1][j], 0, 0, 0);
    }
  }
  // epilogue 1 -> Ts (each wave writes its own col slice; barrier after)
#pragma unroll
  for (int j = 0; j < 8; ++j) {
    const int col  = wave * 128 + j * 16 + fl;
    const float bi = __bfloat162float(b1c[col]);
#pragma unroll
    for (int i = 0; i < 2; ++i) {
#pragma unroll
      for (int r = 0; r < 4; ++r) {
        const int row = i * 16 + rb + r;
        float v = fmaxf(acc[i][j][r] + bi, 0.f);
        if (mask[m0 + row] == 0) v = 0.f;
        Ts[row * 520 + col] = __float2bfloat16(v);
      }
    }
  }
#pragma unroll
  for (int i = 0; i < 2; ++i)
#pragma unroll
    for (int j = 0; j < 8; ++j) acc[i][j] = (f32x4){0.f, 0.f, 0.f, 0.f};
  __syncthreads();  // Ts complete before any stage-2 read

  // ---- stage 2a: acc = Ts @ w2^T  (A straight from LDS, no restage)
  for (int k0 = 0; k0 < OO; k0 += 32) {
    __syncthreads();
#pragma unroll
    for (int c = 0; c < 8; ++c)
      gload_lds16(w2c + (size_t)(wave * 128 + c * 16 + glr) * OO + k0 + glc,
                  (char*)Bsm + wave * 8192 + c * 1024 + lane * 16);
    __syncthreads();

    short8 af0 = *(const short8*)&Ts[fl * 520 + k0 + fk];
    short8 af1 = *(const short8*)&Ts[(16 + fl) * 520 + k0 + fk];
#pragma unroll
    for (int j = 0; j < 8; ++j) {
      const short8 bfr = *(const short8*)&Bsm[(wave * 128 + j * 16 + fl) * 32 + fk];
      acc[0][j] = __builtin_amdgcn_mfma_f32_16x16x32_bf16(af0, bfr, acc[0][j], 0, 0, 0);
      acc[1][j] = __builtin_amdgcn_mfma_f32_16x16x32_bf16(af1, bfr, acc[1][j], 0, 0, 0);
    }
  }

  // ---- stage 2b: acc += x @ wr^T  (x fp32, register convert)
  for (int k0 = 0; k0 < DD; k0 += 32) {
    __syncthreads();
    {
      float4 v = *(const float4*)(xf + (size_t)(m0 + sr) * DD + k0 + sc);
      *(uint2*)&Asm[sr * 32 + sc] = cvt4(v);
    }
#pragma unroll
    for (int c = 0; c < 8; ++c)
      gload_lds16(wrc + (size_t)(wave * 128 + c * 16 + glr) * DD + k0 + glc,
                  (char*)Bsm + wave * 8192 + c * 1024 + lane * 16);
    __syncthreads();

    short8 af0 = *(const short8*)&Asm[fl * 32 + fk];
    short8 af1 = *(const short8*)&Asm[(16 + fl) * 32 + fk];
#pragma unroll
    for (int j = 0; j < 8; ++j) {
      const short8 bfr = *(const short8*)&Bsm[(wave * 128 + j * 16 + fl) * 32 + fk];
      acc[0][j] = __builtin_amdgcn_mfma_f32_16x16x32_bf16(af0, bfr, acc[0][j], 0, 0, 0);
      acc[1][j] = __builtin_amdgcn_mfma_f32_16x16x32_bf16(af1, bfr, acc[1][j], 0, 0, 0);
    }
  }

  // epilogue 2 -> fp32 out
#pragma unroll
  for (int j = 0; j < 8; ++j) {
    const int col   = wave * 128 + j * 16 + fl;
    const float b2v = __bfloat162float(b2c[col]);
    const float brv = __bfloat162float(brc[col]);
#pragma unroll
    for (int i = 0; i < 2; ++i) {
#pragma unroll
      for (int r = 0; r < 4; ++r) {
        const int row = m0 + i * 16 + rb + r;
        const float v = acc[i][j][r] + brv + (mask[row] != 0 ? b2v : 0.f);
        outf[(size_t)row * OO + col] = 0.5f * v;
      }
    }
  }
}

// ---------------------------------------------------------------------------
// Attention (round-11, verified): 128-row Q tile, 512 threads (8 waves x 16
// q-rows). S^T trick (A=K, B=Q): packed b64 P-writes, float4 mask-bias,
// scalar lsum. Q pre-scaled by 0.125*log2(e); Msf fuses mask + shift.
// blockIdx = qblk*64 + bh (XCD-local K/V).
// ---------------------------------------------------------------------------
__global__ __launch_bounds__(512) void attn_kernel(
    const __hip_bfloat16* __restrict__ Qb, const __hip_bfloat16* __restrict__ Kb,
    const __hip_bfloat16* __restrict__ Vt, const __hip_bfloat16* __restrict__ slw,
    const int* __restrict__ mask, __hip_bfloat16* __restrict__ hb) {
  __shared__ __hip_bfloat16 Qs[128 * 72];
  __shared__ __hip_bfloat16 Ks[64 * 72];
  __shared__ __hip_bfloat16 Vs[64 * 72];
  __shared__ __hip_bfloat16 Ps[128 * 72];
  __shared__ float Msf[NN];

  const int tid  = threadIdx.x;
  const int wave = tid >> 6;
  const int lane = tid & 63;
  const int fl   = lane & 15;
  const int quad = lane >> 4;
  const int fk   = quad * 8;
  const int rb   = quad * 4;
  const int bh   = blockIdx.x & 63;
  const int qblk = blockIdx.x >> 6;
  const int b    = bh >> 3;
  const int head = bh & 7;
  const int q0   = qblk * 128;

  const float slwL2 = __bfloat162float(slw[head]) * 1.44269504f;

  {
    const int srow = tid >> 2;
    const int sc   = (tid & 3) * 16;
    const __hip_bfloat16* qg = Qb + ((size_t)bh * NN + q0) * HD;
    uint4 v0 = *(const uint4*)(qg + srow * HD + sc);
    uint4 v1 = *(const uint4*)(qg + srow * HD + sc + 8);
    *(uint4*)&Qs[srow * 72 + sc] = v0;
    *(uint4*)&Qs[srow * 72 + sc + 8] = v1;
#pragma unroll
    for (int k = 0; k < 2; ++k) {
      const int idx = tid * 2 + k;
      Msf[idx] = (mask[b * NN + idx] != 0) ? KSHIFT : KMASKED;
    }
  }
  __syncthreads();
  const short8 qa0 = *(const short8*)&Qs[(wave * 16 + fl) * 72 + fk];
  const short8 qa1 = *(const short8*)&Qs[(wave * 16 + fl) * 72 + fk + 32];

  const int srow2 = tid >> 3;
  const int sc2   = (tid & 7) * 8;

  float lsum = 0.f;
  f32x4 Oacc[4];
#pragma unroll
  for (int t = 0; t < 4; ++t) Oacc[t] = (f32x4){0.f, 0.f, 0.f, 0.f};

  const int kbdiag = 2 * qblk + (wave >> 2);

  for (int kb = 0; kb < NN / 64; ++kb) {
    const int kbase = kb * 64;
    __syncthreads();
    {
      const __hip_bfloat16* kg = Kb + ((size_t)bh * NN + kbase) * HD;
      uint4 v0 = *(const uint4*)(kg + srow2 * HD + sc2);
      *(uint4*)&Ks[srow2 * 72 + sc2] = v0;
      const __hip_bfloat16* vg = Vt + ((size_t)bh * HD + srow2) * NN + kbase;
      uint4 w0 = *(const uint4*)(vg + sc2);
      *(uint4*)&Vs[srow2 * 72 + sc2] = w0;
    }
    __syncthreads();

    f32x4 sfr[4];
#pragma unroll
    for (int j = 0; j < 4; ++j) {
      const short8 kf0 = *(const short8*)&Ks[(j * 16 + fl) * 72 + fk];
      const short8 kf1 = *(const short8*)&Ks[(j * 16 + fl) * 72 + fk + 32];
      f32x4 z = (f32x4){0.f, 0.f, 0.f, 0.f};
      z = __builtin_amdgcn_mfma_f32_16x16x32_bf16(kf0, qa0, z, 0, 0, 0);
      z = __builtin_amdgcn_mfma_f32_16x16x32_bf16(kf1, qa1, z, 0, 0, 0);
      sfr[j] = z;
    }

    if (kb == kbdiag) {
      if ((fl >> 2) == quad) sfr[wave & 3][fl & 3] += slwL2;
    }

#pragma unroll
    for (int j = 0; j < 4; ++j) {
      const f32x4 mb4 = *(const f32x4*)&Msf[kbase + j * 16 + quad * 4];
      union { short4v s; __hip_bfloat16 h[4]; } pu;
      float ps = 0.f;
#pragma unroll
      for (int e = 0; e < 4; ++e) {
        const float pv = exp2f(sfr[j][e] + mb4[e]);
        ps += pv;
        pu.h[e] = __float2bfloat16(pv);
      }
      lsum += ps;
      *(short4v*)&Ps[(wave * 16 + fl) * 72 + j * 16 + quad * 4] = pu.s;
    }

    const short8 pa0 = *(const short8*)&Ps[(wave * 16 + fl) * 72 + fk];
    const short8 pa1 = *(const short8*)&Ps[(wave * 16 + fl) * 72 + fk + 32];
#pragma unroll
    for (int t = 0; t < 4; ++t) {
      const short8 vf0 = *(const short8*)&Vs[(t * 16 + fl) * 72 + fk];
      const short8 vf1 = *(const short8*)&Vs[(t * 16 + fl) * 72 + fk + 32];
      Oacc[t] = __builtin_amdgcn_mfma_f32_16x16x32_bf16(pa0, vf0, Oacc[t], 0, 0, 0);
      Oacc[t] = __builtin_amdgcn_mfma_f32_16x16x32_bf16(pa1, vf1, Oacc[t], 0, 0, 0);
    }
  }

  float l = lsum;
  l += __shfl_xor(l, 16, 64);
  l += __shfl_xor(l, 32, 64);
  const int qrow_me = q0 + wave * 16 + fl;
  const float qm = (mask[b * NN + qrow_me] != 0) ? 1.f : 0.f;
  const float sf = qm / fmaxf(l, 1e-30f);

  float scl[4];
#pragma unroll
  for (int r = 0; r < 4; ++r) scl[r] = __shfl(sf, rb + r, 64);

#pragma unroll
  for (int t = 0; t < 4; ++t) {
    const int d = t * 16 + fl;
#pragma unroll
    for (int r = 0; r < 4; ++r) {
      const int qrow_g = q0 + wave * 16 + rb + r;
      hb[(size_t)(b * NN + qrow_g) * OO + head * HD + d] =
          __float2bfloat16(Oacc[t][r] * scl[r]);
    }
  }
}

extern "C" void kernel_launch(void* const* d_in, const int* in_sizes, int n_in,
                              void* d_out, int out_size, void* d_ws, size_t ws_size,
                              hipStream_t stream) {
  const float* x_raw    = (const float*)d_in[0];
  const int* mask       = (const int*)d_in[2];
  const float* slw_raw  = (const float*)d_in[3];
  const float* qkvw_raw = (const float*)d_in[4];
  const float* qkvb_raw = (const float*)d_in[5];
  const float* w1_raw   = (const float*)d_in[6];
  const float* b1_raw   = (const float*)d_in[7];
  const float* w2_raw   = (const float*)d_in[8];
  const float* b2_raw   = (const float*)d_in[9];
  const float* wr_raw   = (const float*)d_in[10];
  const float* br_raw   = (const float*)d_in[11];
  float* outf           = (float*)d_out;

  __hip_bfloat16* p = (__hip_bfloat16*)d_ws;
  __hip_bfloat16* qkvwc = p; p += 3 * OO * DD;
  __hip_bfloat16* w1c   = p; p += OO * OO;
  __hip_bfloat16* w2c   = p; p += OO * OO;
  __hip_bfloat16* wrc   = p; p += OO * DD;
  __hip_bfloat16* qkvbc = p; p += 3 * OO;
  __hip_bfloat16* b1c   = p; p += OO;
  __hip_bfloat16* b2c   = p; p += OO;
  __hip_bfloat16* brc   = p; p += OO;
  __hip_bfloat16* slwc  = p; p += 64;
  const size_t ebuf = (size_t)BB * HH * NN * HD;
  __hip_bfloat16* Qb = p; p += ebuf;
  __hip_bfloat16* Kb = p; p += ebuf;
  __hip_bfloat16* Vb = p; p += ebuf;   // V^T layout [B,H,64,N]
  __hip_bfloat16* hb = p; p += ebuf;   // attention out (ws: ffn reads h while
                                       // writing d_out — must not alias)

  if (ws_size < (size_t)((char*)p - (char*)d_ws)) return;

  // 0) weight/bias fp32 -> bf16 (x handled in-GEMM)
  ConvArgs ca;
  ca.src[0] = qkvw_raw; ca.dst[0] = qkvwc; ca.n4[0] = 3 * OO * DD / 4;
  ca.src[1] = w1_raw;   ca.dst[1] = w1c;   ca.n4[1] = OO * OO / 4;
  ca.src[2] = w2_raw;   ca.dst[2] = w2c;   ca.n4[2] = OO * OO / 4;
  ca.src[3] = wr_raw;   ca.dst[3] = wrc;   ca.n4[3] = OO * DD / 4;
  ca.src[4] = qkvb_raw; ca.dst[4] = qkvbc; ca.n4[4] = 3 * OO / 4;
  ca.src[5] = b1_raw;   ca.dst[5] = b1c;   ca.n4[5] = OO / 4;
  ca.src[6] = b2_raw;   ca.dst[6] = b2c;   ca.n4[6] = OO / 4;
  ca.src[7] = br_raw;   ca.dst[7] = brc;   ca.n4[7] = OO / 4;
  ca.src[8] = slw_raw;  ca.dst[8] = slwc;  ca.n4[8] = HH / 4;
  convert_kernel<<<dim3(64, SEG_N), 256, 0, stream>>>(ca);

  // 1) qkv projection (x read fp32); Q pre-scaled, K row-major, V transposed
  gemm_qkv<<<dim3(3 * OO / 128, MM / 128), 256, 0, stream>>>(
      x_raw, qkvwc, qkvbc, Qb, Kb, Vb, DD);
  // 2) attention (+ query fmask) -> hb (ws)
  attn_kernel<<<BB * HH * (NN / 128), 512, 0, stream>>>(Qb, Kb, Vb, slwc, mask, hb);
  // 3) fused FFN + residual -> fp32 d_out
  ffn_fused<<<MM / 32, 256, 0, stream>>>(hb, x_raw, w1c, w2c, wrc, b1c, b2c,
                                         brc, mask, outf);
}

// Round 14
// 215.609 us; speedup vs baseline: 1.1381x; 1.1381x over previous
//
#include <hip/hip_runtime.h>
#include <hip/hip_bf16.h>

typedef __attribute__((ext_vector_type(8))) short short8;
typedef __attribute__((ext_vector_type(4))) float f32x4;
typedef __attribute__((ext_vector_type(4))) short short4v;

// Problem constants
#define BB 8
#define NN 1024
#define DD 512
#define OO 512
#define HH 8
#define HD 64
#define MM (BB * NN)  // 8192

#define QSC 0.18033688f       // 0.125 * log2(e): folded into Q at projection
#define KSHIFT -11.54156032f  // -8*log2(e): softmax shift, fused into key bias
#define KMASKED -30000.0f     // masked key: exp2 underflows to exactly 0

// Async global->LDS, 16B/lane (m97 recipe). LDS dest = wave-uniform base +
// lane*16 -> unpadded tiles.
__device__ __forceinline__ void gload_lds16(const void* g, void* l) {
  __builtin_amdgcn_global_load_lds(
      (const __attribute__((address_space(1))) void*)g,
      (__attribute__((address_space(3))) void*)l, 16, 0, 0);
}

__device__ __forceinline__ uint2 cvt4(float4 v) {
  union { uint2 u; __hip_bfloat16 h[4]; } t;
  t.h[0] = __float2bfloat16(v.x);
  t.h[1] = __float2bfloat16(v.y);
  t.h[2] = __float2bfloat16(v.z);
  t.h[3] = __float2bfloat16(v.w);
  return t.u;
}

// ---------------------------------------------------------------------------
// Input conversion. PROVEN: float inputs fp32, mask int32 {0,1}, output fp32.
// ---------------------------------------------------------------------------
#define SEG_N 10
struct ConvArgs {
  const float* src[SEG_N];
  __hip_bfloat16* dst[SEG_N];
  int n4[SEG_N];
};

__global__ void convert_kernel(ConvArgs a) {
  const int t = blockIdx.y;
  const int n4 = a.n4[t];
  const float4* fs = (const float4*)a.src[t];
  uint2* d = (uint2*)a.dst[t];
  for (int i = blockIdx.x * blockDim.x + threadIdx.x; i < n4;
       i += gridDim.x * blockDim.x)
    d[i] = cvt4(fs[i]);
}

// ---------------------------------------------------------------------------
// 128x128-tile GEMM (global_load_lds both sides), qkv epilogue.
// 1D grid of 768, XCD-banded swizzle: XCD k owns rows [1024k, 1024k+1024)
// (x-band 1 MB bf16, L2-resident -> x fetched once per XCD, not 4x).
// Q (pre-scaled QSC), K -> [B,H,N,64]; V -> [B,H,64,N] transposed via LDS.
// ---------------------------------------------------------------------------
__global__ __launch_bounds__(256) void gemm_qkv(
    const __hip_bfloat16* __restrict__ A0, const __hip_bfloat16* __restrict__ B0,
    const __hip_bfloat16* __restrict__ bias0,
    __hip_bfloat16* __restrict__ out0, __hip_bfloat16* __restrict__ out1,
    __hip_bfloat16* __restrict__ out2, int Kd) {
  __shared__ __align__(16) __hip_bfloat16 smem[8192];  // As 128x32 | Bs 128x32
  __hip_bfloat16* As = smem;
  __hip_bfloat16* Bs = smem + 4096;

  const int tid  = threadIdx.x;
  const int wave = tid >> 6;
  const int lane = tid & 63;
  const int fl   = lane & 15;
  const int fk   = (lane >> 4) * 8;
  const int wm   = (wave & 1) * 64;
  const int wn   = (wave >> 1) * 64;
  // XCD-banded swizzle (768 blocks = 64 rowparts x 12 colparts)
  const int bid     = blockIdx.x;
  const int rowpart = 8 * (bid & 7) + ((bid >> 3) & 7);
  const int colpart = bid >> 6;
  const int m0 = rowpart * 128;
  const int n0 = colpart * 128;
  const int glr  = lane >> 2;
  const int glc  = (lane & 3) * 8;

  f32x4 acc[4][4];
#pragma unroll
  for (int i = 0; i < 4; ++i)
#pragma unroll
    for (int j = 0; j < 4; ++j) acc[i][j] = (f32x4){0.f, 0.f, 0.f, 0.f};

  char* lb = (char*)smem;
  for (int k0 = 0; k0 < Kd; k0 += 32) {
    __syncthreads();
    gload_lds16(A0 + (size_t)(m0 + wave * 16 + glr) * Kd + k0 + glc,
                lb + wave * 1024 + lane * 16);
    gload_lds16(A0 + (size_t)(m0 + 64 + wave * 16 + glr) * Kd + k0 + glc,
                lb + (wave + 4) * 1024 + lane * 16);
    gload_lds16(B0 + (size_t)(n0 + wave * 16 + glr) * Kd + k0 + glc,
                lb + 8192 + wave * 1024 + lane * 16);
    gload_lds16(B0 + (size_t)(n0 + 64 + wave * 16 + glr) * Kd + k0 + glc,
                lb + 8192 + (wave + 4) * 1024 + lane * 16);
    __syncthreads();

    short8 af[4], bfr[4];
#pragma unroll
    for (int i = 0; i < 4; ++i)
      af[i] = *(const short8*)&As[(wm + i * 16 + fl) * 32 + fk];
#pragma unroll
    for (int j = 0; j < 4; ++j)
      bfr[j] = *(const short8*)&Bs[(wn + j * 16 + fl) * 32 + fk];
#pragma unroll
    for (int i = 0; i < 4; ++i)
#pragma unroll
      for (int j = 0; j < 4; ++j)
        acc[i][j] = __builtin_amdgcn_mfma_f32_16x16x32_bf16(af[i], bfr[j],
                                                            acc[i][j], 0, 0, 0);
  }

  const int rb = (lane >> 4) * 4;
  const int part = n0 >> 9;  // block-uniform
  if (part < 2) {
    __hip_bfloat16* dst = (part == 0) ? out0 : out1;
    const float scf = (part == 0) ? QSC : 1.0f;
#pragma unroll
    for (int j = 0; j < 4; ++j) {
      const int colb  = n0 + wn + j * 16;
      const int o     = colb & 511;
      const int headq = o >> 6;
      const int d     = (o & 63) + fl;
      const float bi  = __bfloat162float(bias0[colb + fl]);
#pragma unroll
      for (int i = 0; i < 4; ++i) {
#pragma unroll
        for (int r = 0; r < 4; ++r) {
          const int row = m0 + wm + i * 16 + rb + r;
          const int bb  = row >> 10;
          const int nn  = row & 1023;
          dst[((size_t)((bb << 3) + headq) * NN + nn) * HD + d] =
              __float2bfloat16((acc[i][j][r] + bi) * scf);
        }
      }
    }
  } else {
    // V: transpose 64x16 pieces through LDS, coalesced dwordx4 stores
    __syncthreads();  // uniform; smem free for scratch
    __hip_bfloat16* tsc = smem + wave * 1120;  // 16 x 70 per wave
    const int bb  = (m0 + wm) >> 10;
    const int nnb = (m0 + wm) & 1023;
    const int dl  = lane >> 2;
    const int cc  = (lane & 3) * 16;
#pragma unroll
    for (int j = 0; j < 4; ++j) {
      const int colb  = n0 + wn + j * 16;
      const int o     = colb & 511;
      const int headq = o >> 6;
      const int dbase = o & 63;
      const float bi  = __bfloat162float(bias0[colb + fl]);
#pragma unroll
      for (int i = 0; i < 4; ++i) {
#pragma unroll
        for (int r = 0; r < 4; ++r) {
          const int rr = i * 16 + rb + r;
          tsc[fl * 70 + rr] = __float2bfloat16(acc[i][j][r] + bi);
        }
      }
      uint4 r0 = *(const uint4*)&tsc[dl * 70 + cc];
      uint4 r1 = *(const uint4*)&tsc[dl * 70 + cc + 8];
      __hip_bfloat16* vdst =
          out2 + ((size_t)((bb << 3) + headq) * HD + dbase + dl) * NN + nnb;
      *(uint4*)&vdst[cc] = r0;
      *(uint4*)&vdst[cc + 8] = r1;
    }
  }
}

// ---------------------------------------------------------------------------
// 64x64-tile GEMM (global_load_lds), FFN GEMMs. 1D grid of 1024, XCD-banded:
// XCD k owns rows [1024k, 1024k+1024) -> ffn1's t-band is read back by the
// SAME XCD's ffn2 blocks (1 MB, L2-hit).
// MODE 1: relu(acc + bias0) * rowmask -> out0 bf16
// MODE 2: 0.5*(accA+accB + bias1 + (rowmask ? bias0 : 0)) -> outf fp32
// ---------------------------------------------------------------------------
template <int MODE>
__global__ __launch_bounds__(256) void gemm64(
    const __hip_bfloat16* __restrict__ A0, const __hip_bfloat16* __restrict__ B0,
    const __hip_bfloat16* __restrict__ A1, const __hip_bfloat16* __restrict__ B1,
    const __hip_bfloat16* __restrict__ bias0, const __hip_bfloat16* __restrict__ bias1,
    const int* __restrict__ mask,
    __hip_bfloat16* __restrict__ out0, float* __restrict__ outf,
    int N, int Kd) {
  __shared__ __align__(16) __hip_bfloat16 smem[4096];  // As 64x32 | Bs 64x32
  __hip_bfloat16* As = smem;
  __hip_bfloat16* Bs = smem + 2048;

  const int tid  = threadIdx.x;
  const int wave = tid >> 6;
  const int lane = tid & 63;
  const int fl   = lane & 15;
  const int fk   = (lane >> 4) * 8;
  const int wm   = (wave & 1) * 32;
  const int wn   = (wave >> 1) * 32;
  // XCD-banded swizzle (1024 blocks = 128 rowparts x 8 colparts)
  const int bid     = blockIdx.x;
  const int rowpart = 16 * (bid & 7) + ((bid >> 3) & 15);
  const int colpart = bid >> 7;
  const int m0 = rowpart * 64;
  const int n0 = colpart * 64;
  const int glr  = lane >> 2;
  const int glc  = (lane & 3) * 8;

  f32x4 acc[2][2];
#pragma unroll
  for (int i = 0; i < 2; ++i)
#pragma unroll
    for (int j = 0; j < 2; ++j) acc[i][j] = (f32x4){0.f, 0.f, 0.f, 0.f};

  char* lb = (char*)smem;
  const int npairs = (MODE == 2) ? 2 : 1;
  for (int p = 0; p < npairs; ++p) {
    const __hip_bfloat16* Ap = (p == 0) ? A0 : A1;
    const __hip_bfloat16* Bp = (p == 0) ? B0 : B1;
    for (int k0 = 0; k0 < Kd; k0 += 32) {
      __syncthreads();
      gload_lds16(Ap + (size_t)(m0 + wave * 16 + glr) * Kd + k0 + glc,
                  lb + wave * 1024 + lane * 16);
      gload_lds16(Bp + (size_t)(n0 + wave * 16 + glr) * Kd + k0 + glc,
                  lb + 4096 + wave * 1024 + lane * 16);
      __syncthreads();

      short8 af[2], bfr[2];
#pragma unroll
      for (int i = 0; i < 2; ++i)
        af[i] = *(const short8*)&As[(wm + i * 16 + fl) * 32 + fk];
#pragma unroll
      for (int j = 0; j < 2; ++j)
        bfr[j] = *(const short8*)&Bs[(wn + j * 16 + fl) * 32 + fk];
#pragma unroll
      for (int i = 0; i < 2; ++i)
#pragma unroll
        for (int j = 0; j < 2; ++j)
          acc[i][j] = __builtin_amdgcn_mfma_f32_16x16x32_bf16(af[i], bfr[j],
                                                              acc[i][j], 0, 0, 0);
    }
  }

  const int rb = (lane >> 4) * 4;
  if (MODE == 1) {
#pragma unroll
    for (int j = 0; j < 2; ++j) {
      const int col  = n0 + wn + j * 16 + fl;
      const float bi = __bfloat162float(bias0[col]);
#pragma unroll
      for (int i = 0; i < 2; ++i) {
#pragma unroll
        for (int r = 0; r < 4; ++r) {
          const int row = m0 + wm + i * 16 + rb + r;
          float v = fmaxf(acc[i][j][r] + bi, 0.f);
          if (mask[row] == 0) v = 0.f;
          out0[(size_t)row * N + col] = __float2bfloat16(v);
        }
      }
    }
  } else {
#pragma unroll
    for (int j = 0; j < 2; ++j) {
      const int col   = n0 + wn + j * 16 + fl;
      const float b2v = __bfloat162float(bias0[col]);
      const float brv = __bfloat162float(bias1[col]);
#pragma unroll
      for (int i = 0; i < 2; ++i) {
#pragma unroll
        for (int r = 0; r < 4; ++r) {
          const int row = m0 + wm + i * 16 + rb + r;
          const float v = acc[i][j][r] + brv + (mask[row] != 0 ? b2v : 0.f);
          outf[(size_t)row * N + col] = 0.5f * v;
        }
      }
    }
  }
}

// ---------------------------------------------------------------------------
// Attention (verified): 128-row Q tile, 512 threads (8 waves x 16 q-rows).
// S^T trick (A=K, B=Q): packed b64 P-writes, float4 mask-bias, scalar lsum.
// Q pre-scaled by 0.125*log2(e); Msf fuses mask + shift (log2 domain).
// blockIdx = qblk*64 + bh (XCD-local K/V).
// ---------------------------------------------------------------------------
__global__ __launch_bounds__(512) void attn_kernel(
    const __hip_bfloat16* __restrict__ Qb, const __hip_bfloat16* __restrict__ Kb,
    const __hip_bfloat16* __restrict__ Vt, const __hip_bfloat16* __restrict__ slw,
    const int* __restrict__ mask, __hip_bfloat16* __restrict__ hb) {
  __shared__ __hip_bfloat16 Qs[128 * 72];
  __shared__ __hip_bfloat16 Ks[64 * 72];
  __shared__ __hip_bfloat16 Vs[64 * 72];
  __shared__ __hip_bfloat16 Ps[128 * 72];
  __shared__ float Msf[NN];

  const int tid  = threadIdx.x;
  const int wave = tid >> 6;
  const int lane = tid & 63;
  const int fl   = lane & 15;
  const int quad = lane >> 4;
  const int fk   = quad * 8;
  const int rb   = quad * 4;
  const int bh   = blockIdx.x & 63;
  const int qblk = blockIdx.x >> 6;
  const int b    = bh >> 3;
  const int head = bh & 7;
  const int q0   = qblk * 128;

  const float slwL2 = __bfloat162float(slw[head]) * 1.44269504f;

  {
    const int srow = tid >> 2;
    const int sc   = (tid & 3) * 16;
    const __hip_bfloat16* qg = Qb + ((size_t)bh * NN + q0) * HD;
    uint4 v0 = *(const uint4*)(qg + srow * HD + sc);
    uint4 v1 = *(const uint4*)(qg + srow * HD + sc + 8);
    *(uint4*)&Qs[srow * 72 + sc] = v0;
    *(uint4*)&Qs[srow * 72 + sc + 8] = v1;
#pragma unroll
    for (int k = 0; k < 2; ++k) {
      const int idx = tid * 2 + k;
      Msf[idx] = (mask[b * NN + idx] != 0) ? KSHIFT : KMASKED;
    }
  }
  __syncthreads();
  const short8 qa0 = *(const short8*)&Qs[(wave * 16 + fl) * 72 + fk];
  const short8 qa1 = *(const short8*)&Qs[(wave * 16 + fl) * 72 + fk + 32];

  const int srow2 = tid >> 3;
  const int sc2   = (tid & 7) * 8;

  float lsum = 0.f;
  f32x4 Oacc[4];
#pragma unroll
  for (int t = 0; t < 4; ++t) Oacc[t] = (f32x4){0.f, 0.f, 0.f, 0.f};

  const int kbdiag = 2 * qblk + (wave >> 2);

  for (int kb = 0; kb < NN / 64; ++kb) {
    const int kbase = kb * 64;
    __syncthreads();
    {
      const __hip_bfloat16* kg = Kb + ((size_t)bh * NN + kbase) * HD;
      uint4 v0 = *(const uint4*)(kg + srow2 * HD + sc2);
      *(uint4*)&Ks[srow2 * 72 + sc2] = v0;
      const __hip_bfloat16* vg = Vt + ((size_t)bh * HD + srow2) * NN + kbase;
      uint4 w0 = *(const uint4*)(vg + sc2);
      *(uint4*)&Vs[srow2 * 72 + sc2] = w0;
    }
    __syncthreads();

    f32x4 sfr[4];
#pragma unroll
    for (int j = 0; j < 4; ++j) {
      const short8 kf0 = *(const short8*)&Ks[(j * 16 + fl) * 72 + fk];
      const short8 kf1 = *(const short8*)&Ks[(j * 16 + fl) * 72 + fk + 32];
      f32x4 z = (f32x4){0.f, 0.f, 0.f, 0.f};
      z = __builtin_amdgcn_mfma_f32_16x16x32_bf16(kf0, qa0, z, 0, 0, 0);
      z = __builtin_amdgcn_mfma_f32_16x16x32_bf16(kf1, qa1, z, 0, 0, 0);
      sfr[j] = z;
    }

    if (kb == kbdiag) {
      if ((fl >> 2) == quad) sfr[wave & 3][fl & 3] += slwL2;
    }

#pragma unroll
    for (int j = 0; j < 4; ++j) {
      const f32x4 mb4 = *(const f32x4*)&Msf[kbase + j * 16 + quad * 4];
      union { short4v s; __hip_bfloat16 h[4]; } pu;
      float ps = 0.f;
#pragma unroll
      for (int e = 0; e < 4; ++e) {
        const float pv = exp2f(sfr[j][e] + mb4[e]);
        ps += pv;
        pu.h[e] = __float2bfloat16(pv);
      }
      lsum += ps;
      *(short4v*)&Ps[(wave * 16 + fl) * 72 + j * 16 + quad * 4] = pu.s;
    }

    const short8 pa0 = *(const short8*)&Ps[(wave * 16 + fl) * 72 + fk];
    const short8 pa1 = *(const short8*)&Ps[(wave * 16 + fl) * 72 + fk + 32];
#pragma unroll
    for (int t = 0; t < 4; ++t) {
      const short8 vf0 = *(const short8*)&Vs[(t * 16 + fl) * 72 + fk];
      const short8 vf1 = *(const short8*)&Vs[(t * 16 + fl) * 72 + fk + 32];
      Oacc[t] = __builtin_amdgcn_mfma_f32_16x16x32_bf16(pa0, vf0, Oacc[t], 0, 0, 0);
      Oacc[t] = __builtin_amdgcn_mfma_f32_16x16x32_bf16(pa1, vf1, Oacc[t], 0, 0, 0);
    }
  }

  float l = lsum;
  l += __shfl_xor(l, 16, 64);
  l += __shfl_xor(l, 32, 64);
  const int qrow_me = q0 + wave * 16 + fl;
  const float qm = (mask[b * NN + qrow_me] != 0) ? 1.f : 0.f;
  const float sf = qm / fmaxf(l, 1e-30f);

  float scl[4];
#pragma unroll
  for (int r = 0; r < 4; ++r) scl[r] = __shfl(sf, rb + r, 64);

#pragma unroll
  for (int t = 0; t < 4; ++t) {
    const int d = t * 16 + fl;
#pragma unroll
    for (int r = 0; r < 4; ++r) {
      const int qrow_g = q0 + wave * 16 + rb + r;
      hb[(size_t)(b * NN + qrow_g) * OO + head * HD + d] =
          __float2bfloat16(Oacc[t][r] * scl[r]);
    }
  }
}

extern "C" void kernel_launch(void* const* d_in, const int* in_sizes, int n_in,
                              void* d_out, int out_size, void* d_ws, size_t ws_size,
                              hipStream_t stream) {
  const float* x_raw    = (const float*)d_in[0];
  const int* mask       = (const int*)d_in[2];
  const float* slw_raw  = (const float*)d_in[3];
  const float* qkvw_raw = (const float*)d_in[4];
  const float* qkvb_raw = (const float*)d_in[5];
  const float* w1_raw   = (const float*)d_in[6];
  const float* b1_raw   = (const float*)d_in[7];
  const float* w2_raw   = (const float*)d_in[8];
  const float* b2_raw   = (const float*)d_in[9];
  const float* wr_raw   = (const float*)d_in[10];
  const float* br_raw   = (const float*)d_in[11];
  float* outf           = (float*)d_out;

  __hip_bfloat16* p = (__hip_bfloat16*)d_ws;
  __hip_bfloat16* xc    = p; p += (size_t)MM * DD;
  __hip_bfloat16* qkvwc = p; p += 3 * OO * DD;
  __hip_bfloat16* w1c   = p; p += OO * OO;
  __hip_bfloat16* w2c   = p; p += OO * OO;
  __hip_bfloat16* wrc   = p; p += OO * DD;
  __hip_bfloat16* qkvbc = p; p += 3 * OO;
  __hip_bfloat16* b1c   = p; p += OO;
  __hip_bfloat16* b2c   = p; p += OO;
  __hip_bfloat16* brc   = p; p += OO;
  __hip_bfloat16* slwc  = p; p += 64;
  const size_t ebuf = (size_t)BB * HH * NN * HD;
  __hip_bfloat16* Qb = p; p += ebuf;
  __hip_bfloat16* Kb = p; p += ebuf;
  __hip_bfloat16* Vb = p; p += ebuf;   // V^T layout [B,H,64,N]
  __hip_bfloat16* hb = (__hip_bfloat16*)d_out;  // attn out scratch in d_out;
                                                // fully consumed by ffn1
  __hip_bfloat16* tb = Kb;  // ffn hidden aliases Kb (dead after attention)

  if (ws_size < (size_t)((char*)p - (char*)d_ws)) return;

  ConvArgs ca;
  ca.src[0] = x_raw;    ca.dst[0] = xc;    ca.n4[0] = MM * DD / 4;
  ca.src[1] = qkvw_raw; ca.dst[1] = qkvwc; ca.n4[1] = 3 * OO * DD / 4;
  ca.src[2] = w1_raw;   ca.dst[2] = w1c;   ca.n4[2] = OO * OO / 4;
  ca.src[3] = w2_raw;   ca.dst[3] = w2c;   ca.n4[3] = OO * OO / 4;
  ca.src[4] = wr_raw;   ca.dst[4] = wrc;   ca.n4[4] = OO * DD / 4;
  ca.src[5] = qkvb_raw; ca.dst[5] = qkvbc; ca.n4[5] = 3 * OO / 4;
  ca.src[6] = b1_raw;   ca.dst[6] = b1c;   ca.n4[6] = OO / 4;
  ca.src[7] = b2_raw;   ca.dst[7] = b2c;   ca.n4[7] = OO / 4;
  ca.src[8] = br_raw;   ca.dst[8] = brc;   ca.n4[8] = OO / 4;
  ca.src[9] = slw_raw;  ca.dst[9] = slwc;  ca.n4[9] = HH / 4;
  convert_kernel<<<dim3(128, SEG_N), 256, 0, stream>>>(ca);

  // 1) qkv projection (XCD-banded); Q pre-scaled, K row-major, V transposed
  gemm_qkv<<<768, 256, 0, stream>>>(xc, qkvwc, qkvbc, Qb, Kb, Vb, DD);
  // 2) attention (+ query fmask) -> hb (scratch inside d_out)
  attn_kernel<<<BB * HH * (NN / 128), 512, 0, stream>>>(Qb, Kb, Vb, slwc, mask, hb);
  // 3) ffn layer 1 (XCD-banded): relu(h@w1^T + b1), masked rows zeroed
  gemm64<1><<<1024, 256, 0, stream>>>(
      hb, w1c, nullptr, nullptr, b1c, nullptr, mask, tb, nullptr, OO, OO);
  // 4) ffn layer 2 + residual (XCD-banded, t-band L2-resident) -> fp32 out
  gemm64<2><<<1024, 256, 0, stream>>>(
      tb, w2c, xc, wrc, b2c, brc, mask, nullptr, outf, OO, DD);
}